// Round 1
// baseline (658.918 us; speedup 1.0000x reference)
//
#include <hip/hip_runtime.h>
#include <hip/hip_bf16.h>

#define D 128

// ---------------- CSR build kernels ----------------

__global__ void k_zero(int* __restrict__ p, int n) {
    int i = blockIdx.x * 256 + threadIdx.x;
    if (i < n) p[i] = 0;
}

__global__ void k_hist(const int* __restrict__ dst, int E, int* __restrict__ deg) {
    int e = blockIdx.x * 256 + threadIdx.x;
    if (e < E) atomicAdd(&deg[dst[e]], 1);
}

__global__ void k_scan1(const int* __restrict__ deg, int* __restrict__ rowptr,
                        int* __restrict__ part, int n) {
    __shared__ int s[256];
    int tid = threadIdx.x;
    int i = blockIdx.x * 256 + tid;
    int v = (i < n) ? deg[i] : 0;
    s[tid] = v;
    __syncthreads();
#pragma unroll
    for (int off = 1; off < 256; off <<= 1) {
        int t = (tid >= off) ? s[tid - off] : 0;
        __syncthreads();
        s[tid] += t;
        __syncthreads();
    }
    if (i < n) rowptr[i] = s[tid] - v;  // exclusive scan within chunk
    if (tid == 255) part[blockIdx.x] = s[255];
}

__global__ void k_scan2(int* __restrict__ part, int nb) {
    if (blockIdx.x == 0 && threadIdx.x == 0) {
        int run = 0;
        for (int b = 0; b < nb; ++b) { int t = part[b]; part[b] = run; run += t; }
    }
}

__global__ void k_scan3(int* __restrict__ rowptr, const int* __restrict__ part, int n, int E) {
    int i = blockIdx.x * 256 + threadIdx.x;
    if (i < n) rowptr[i] += part[i >> 8];
    if (i == 0) rowptr[n] = E;
}

__global__ void k_copy(const int* __restrict__ a, int* __restrict__ b, int n) {
    int i = blockIdx.x * 256 + threadIdx.x;
    if (i < n) b[i] = a[i];
}

__global__ void k_scatter(const int* __restrict__ src, const int* __restrict__ dst, int E,
                          int* __restrict__ cursor, int* __restrict__ col) {
    int e = blockIdx.x * 256 + threadIdx.x;
    if (e < E) {
        int p = atomicAdd(&cursor[dst[e]], 1);
        col[p] = src[e];
    }
}

// ---------------- Aggregation: h[i] = x[i] + sum_{j in adj(i)} x[j] ----------------
// One wave per node; lane l owns features (2l, 2l+1) as float2 -> 512B coalesced per row.

__global__ __launch_bounds__(256) void agg_kernel(const float* __restrict__ X,
                                                  const int* __restrict__ rowptr,
                                                  const int* __restrict__ colidx,
                                                  float* __restrict__ H, int nnodes) {
    int node = blockIdx.x * 4 + (threadIdx.x >> 6);
    if (node >= nnodes) return;
    int lane = threadIdx.x & 63;
    const float2* x2 = (const float2*)X;
    size_t base = (size_t)node * 64 + lane;
    float2 acc = x2[base];
    float2 a1 = {0.f, 0.f};
    int e = rowptr[node], end = rowptr[node + 1];
    for (; e + 3 < end; e += 4) {
        int s0 = colidx[e], s1 = colidx[e + 1], s2 = colidx[e + 2], s3 = colidx[e + 3];
        float2 v0 = x2[(size_t)s0 * 64 + lane];
        float2 v1 = x2[(size_t)s1 * 64 + lane];
        float2 v2 = x2[(size_t)s2 * 64 + lane];
        float2 v3 = x2[(size_t)s3 * 64 + lane];
        acc.x += v0.x + v2.x; acc.y += v0.y + v2.y;
        a1.x  += v1.x + v3.x; a1.y  += v1.y + v3.y;
    }
    for (; e < end; ++e) {
        int s = colidx[e];
        float2 v = x2[(size_t)s * 64 + lane];
        acc.x += v.x; acc.y += v.y;
    }
    acc.x += a1.x; acc.y += a1.y;
    ((float2*)H)[base] = acc;
}

// ---------------- Fused MLP: out = relu( relu(Hin@Wa+ba) @ Wb + bb ) ----------------
// 64 rows/block, 256 threads. Thread (tid) owns rows rB..rB+7, cols 4*cB..4*cB+3.
// h tile and t tile in LDS (32KB each); weights streamed from global (L1/L2-hot).

__device__ __forceinline__ void gemm_tile(const float* __restrict__ sIn,
                                          const float4* __restrict__ W4,
                                          int rB, int cB, float acc[8][4]) {
#pragma unroll 4
    for (int k4 = 0; k4 < 32; ++k4) {
        float4 w0 = W4[(k4 * 4 + 0) * 32 + cB];
        float4 w1 = W4[(k4 * 4 + 1) * 32 + cB];
        float4 w2 = W4[(k4 * 4 + 2) * 32 + cB];
        float4 w3 = W4[(k4 * 4 + 3) * 32 + cB];
#pragma unroll
        for (int i = 0; i < 8; ++i) {
            float4 h = *(const float4*)&sIn[(rB + i) * 128 + k4 * 4];
            acc[i][0] = fmaf(h.x, w0.x, fmaf(h.y, w1.x, fmaf(h.z, w2.x, fmaf(h.w, w3.x, acc[i][0]))));
            acc[i][1] = fmaf(h.x, w0.y, fmaf(h.y, w1.y, fmaf(h.z, w2.y, fmaf(h.w, w3.y, acc[i][1]))));
            acc[i][2] = fmaf(h.x, w0.z, fmaf(h.y, w1.z, fmaf(h.z, w2.z, fmaf(h.w, w3.z, acc[i][2]))));
            acc[i][3] = fmaf(h.x, w0.w, fmaf(h.y, w1.w, fmaf(h.z, w2.w, fmaf(h.w, w3.w, acc[i][3]))));
        }
    }
}

__global__ __launch_bounds__(256) void mlp_kernel(const float* __restrict__ Hin,
                                                  const float* __restrict__ Wa,
                                                  const float* __restrict__ ba,
                                                  const float* __restrict__ Wb,
                                                  const float* __restrict__ bb,
                                                  float* __restrict__ Out, int nrows) {
    __shared__ float hT[64 * 128];
    __shared__ float tT[64 * 128];
    const int tid = threadIdx.x;
    const int rows0 = blockIdx.x * 64;
    const int nvalid = min(64, nrows - rows0);

    // load h tile (zero-fill invalid rows)
    {
        const float4* src = (const float4*)(Hin + (size_t)rows0 * 128);
        float4* dst4 = (float4*)hT;
#pragma unroll
        for (int it = 0; it < 8; ++it) {
            int idx = it * 256 + tid;      // float4 index; row = idx>>5
            float4 v = {0.f, 0.f, 0.f, 0.f};
            if ((idx >> 5) < nvalid) v = src[idx];
            dst4[idx] = v;
        }
    }
    __syncthreads();

    const int rB = (tid >> 5) * 8;
    const int cB = (tid & 31);

    // GEMM1: t = relu(h @ Wa + ba)
    float acc[8][4];
    {
        float4 bv = ((const float4*)ba)[cB];
#pragma unroll
        for (int i = 0; i < 8; ++i) { acc[i][0] = bv.x; acc[i][1] = bv.y; acc[i][2] = bv.z; acc[i][3] = bv.w; }
    }
    gemm_tile(hT, (const float4*)Wa, rB, cB, acc);
#pragma unroll
    for (int i = 0; i < 8; ++i) {
        float4 tv;
        tv.x = fmaxf(acc[i][0], 0.f); tv.y = fmaxf(acc[i][1], 0.f);
        tv.z = fmaxf(acc[i][2], 0.f); tv.w = fmaxf(acc[i][3], 0.f);
        *(float4*)&tT[(rB + i) * 128 + cB * 4] = tv;
    }
    __syncthreads();

    // GEMM2: out = relu(t @ Wb + bb)
    {
        float4 bv = ((const float4*)bb)[cB];
#pragma unroll
        for (int i = 0; i < 8; ++i) { acc[i][0] = bv.x; acc[i][1] = bv.y; acc[i][2] = bv.z; acc[i][3] = bv.w; }
    }
    gemm_tile(tT, (const float4*)Wb, rB, cB, acc);
#pragma unroll
    for (int i = 0; i < 8; ++i) {
        if (rB + i < nvalid) {
            float4 ov;
            ov.x = fmaxf(acc[i][0], 0.f); ov.y = fmaxf(acc[i][1], 0.f);
            ov.z = fmaxf(acc[i][2], 0.f); ov.w = fmaxf(acc[i][3], 0.f);
            *(float4*)&Out[((size_t)rows0 + rB + i) * 128 + cB * 4] = ov;
        }
    }
}

// ---------------- launch ----------------

extern "C" void kernel_launch(void* const* d_in, const int* in_sizes, int n_in,
                              void* d_out, int out_size, void* d_ws, size_t ws_size,
                              hipStream_t stream) {
    const float* x  = (const float*)d_in[0];
    const int*   ei = (const int*)d_in[1];   // [2,E]: src then dst
    const float* W1a = (const float*)d_in[3];
    const float* b1a = (const float*)d_in[4];
    const float* W1b = (const float*)d_in[5];
    const float* b1b = (const float*)d_in[6];
    const float* W2a = (const float*)d_in[7];
    const float* b2a = (const float*)d_in[8];
    const float* W2b = (const float*)d_in[9];
    const float* b2b = (const float*)d_in[10];
    float* out = (float*)d_out;

    const int Nn = in_sizes[0] / D;
    const int E  = in_sizes[1] / 2;
    const int* srcIdx = ei;
    const int* dstIdx = ei + E;

    // workspace layout
    char* w = (char*)d_ws;
    size_t off = 0;
    int* rowptr = (int*)(w + off); off += (size_t)(Nn + 1) * 4;
    off = (off + 255) & ~(size_t)255;
    int* part = (int*)(w + off);   off += 4096;
    int* cursor = (int*)(w + off); off += (size_t)Nn * 4;
    int* colA = (int*)(w + off);   off += (size_t)E * 4;
    off = (off + 255) & ~(size_t)255;
    float* h1 = (float*)(w + off); // Nn*128 floats

    const int nchunk = (Nn + 255) / 256;
    const int gE = (E + 255) / 256;
    const int gN = (Nn + 255) / 256;

    // CSR build (deg accumulated into `cursor` first)
    k_zero<<<gN, 256, 0, stream>>>(cursor, Nn);
    k_hist<<<gE, 256, 0, stream>>>(dstIdx, E, cursor);
    k_scan1<<<nchunk, 256, 0, stream>>>(cursor, rowptr, part, Nn);
    k_scan2<<<1, 64, 0, stream>>>(part, nchunk);
    k_scan3<<<nchunk, 256, 0, stream>>>(rowptr, part, Nn, E);
    k_copy<<<gN, 256, 0, stream>>>(rowptr, cursor, Nn);
    k_scatter<<<gE, 256, 0, stream>>>(srcIdx, dstIdx, E, cursor, colA);

    const int gAgg = (Nn + 3) / 4;
    const int gMlp = (Nn + 63) / 64;

    // Layer 1
    agg_kernel<<<gAgg, 256, 0, stream>>>(x, rowptr, colA, h1, Nn);
    mlp_kernel<<<gMlp, 256, 0, stream>>>(h1, W1a, b1a, W1b, b1b, out, Nn);
    // Layer 2 (layer-1 output lives in d_out, overwritten at the end)
    agg_kernel<<<gAgg, 256, 0, stream>>>(out, rowptr, colA, h1, Nn);
    mlp_kernel<<<gMlp, 256, 0, stream>>>(h1, W2a, b2a, W2b, b2b, out, Nn);
}

// Round 2
// 483.502 us; speedup vs baseline: 1.3628x; 1.3628x over previous
//
#include <hip/hip_runtime.h>
#include <hip/hip_bf16.h>

#define D 128
#define EPB 4096   // edges per binning block

// ---------------- small utils ----------------

__global__ void k_zero(int* __restrict__ p, int n) {
    int i = blockIdx.x * 256 + threadIdx.x;
    if (i < n) p[i] = 0;
}

// ---------------- bucketed CSR build ----------------
// bucket = dst >> 8 (256 nodes per bucket). Edges packed as (src<<8)|(dst&255),
// valid because src < 2^24.

__global__ __launch_bounds__(256) void k_bhist(const int* __restrict__ dst, int E,
                                               int* __restrict__ bucketCnt, int NB) {
    __shared__ int cnt[512];
    int t = threadIdx.x;
    cnt[t] = 0; cnt[t + 256] = 0;
    __syncthreads();
    int e0 = blockIdx.x * EPB;
#pragma unroll
    for (int i = 0; i < EPB / 256; ++i) {
        int e = e0 + i * 256 + t;
        if (e < E) atomicAdd(&cnt[dst[e] >> 8], 1);
    }
    __syncthreads();
    if (cnt[t]) atomicAdd(&bucketCnt[t], cnt[t]);
    if (t + 256 < NB && cnt[t + 256]) atomicAdd(&bucketCnt[t + 256], cnt[t + 256]);
}

__global__ void k_bscan(const int* __restrict__ bucketCnt, int NB, int E,
                        int* __restrict__ bucketBase, int* __restrict__ gCursor) {
    __shared__ int c[512];
    __shared__ int s[256];
    int t = threadIdx.x;
    c[t] = (t < NB) ? bucketCnt[t] : 0;
    c[t + 256] = (t + 256 < NB) ? bucketCnt[t + 256] : 0;
    __syncthreads();
    int v0 = c[2 * t], v1 = c[2 * t + 1];
    int ps = v0 + v1;
    s[t] = ps;
    __syncthreads();
    for (int off = 1; off < 256; off <<= 1) {
        int tv = (t >= off) ? s[t - off] : 0;
        __syncthreads();
        s[t] += tv;
        __syncthreads();
    }
    int ex = s[t] - ps;  // exclusive prefix of pair
    if (2 * t <= NB)     bucketBase[2 * t] = ex;
    if (2 * t + 1 <= NB) bucketBase[2 * t + 1] = ex + v0;
    if (2 * t < NB)      gCursor[2 * t] = ex;
    if (2 * t + 1 < NB)  gCursor[2 * t + 1] = ex + v0;
}

__global__ __launch_bounds__(256) void k_bin(const int* __restrict__ src,
                                             const int* __restrict__ dst, int E,
                                             int* __restrict__ gCursor,
                                             unsigned* __restrict__ binned) {
    __shared__ int cnt[512];
    __shared__ int offs[512];
    __shared__ int c2[512];
    __shared__ int gOff[512];
    __shared__ int s[256];
    __shared__ unsigned staged[EPB];
    __shared__ unsigned short bo[EPB];
    int t = threadIdx.x;
    cnt[t] = 0; cnt[t + 256] = 0;
    c2[t] = 0; c2[t + 256] = 0;
    __syncthreads();

    unsigned pk[EPB / 256];
    int bk[EPB / 256];
    int e0 = blockIdx.x * EPB;
#pragma unroll
    for (int i = 0; i < EPB / 256; ++i) {
        int e = e0 + i * 256 + t;
        int b = -1; unsigned p = 0;
        if (e < E) {
            int dv = dst[e], sv = src[e];
            b = dv >> 8;
            p = ((unsigned)sv << 8) | (unsigned)(dv & 255);
            atomicAdd(&cnt[b], 1);
        }
        pk[i] = p; bk[i] = b;
    }
    __syncthreads();
    // exclusive scan of cnt[0..511] -> offs
    int v0 = cnt[2 * t], v1 = cnt[2 * t + 1];
    int ps = v0 + v1;
    s[t] = ps;
    __syncthreads();
    for (int off = 1; off < 256; off <<= 1) {
        int tv = (t >= off) ? s[t - off] : 0;
        __syncthreads();
        s[t] += tv;
        __syncthreads();
    }
    int ex = s[t] - ps;
    offs[2 * t] = ex;
    offs[2 * t + 1] = ex + v0;
    // reserve global runs (cnt beyond NB is always 0 -> no OOB atomics)
    if (cnt[2 * t])     gOff[2 * t]     = atomicAdd(&gCursor[2 * t], cnt[2 * t]);
    if (cnt[2 * t + 1]) gOff[2 * t + 1] = atomicAdd(&gCursor[2 * t + 1], cnt[2 * t + 1]);
    __syncthreads();
    // place into LDS staging grouped by bucket
#pragma unroll
    for (int i = 0; i < EPB / 256; ++i) {
        int b = bk[i];
        if (b >= 0) {
            int p = offs[b] + atomicAdd(&c2[b], 1);
            staged[p] = pk[i];
            bo[p] = (unsigned short)b;
        }
    }
    __syncthreads();
    int total = s[255];
    for (int p = t; p < total; p += 256) {
        int b = bo[p];
        binned[gOff[b] + (p - offs[b])] = staged[p];
    }
}

__global__ __launch_bounds__(256) void k_csr(const unsigned* __restrict__ binned,
                                             const int* __restrict__ bucketBase,
                                             int* __restrict__ rowptr,
                                             int* __restrict__ colA,
                                             int Nn, int E, int NB) {
    __shared__ int hist[256], loc[256], cur[256], s[256];
    int t = threadIdx.x, b = blockIdx.x;
    int base = bucketBase[b], endb = bucketBase[b + 1];
    int n = endb - base;
    hist[t] = 0; cur[t] = 0;
    __syncthreads();
    for (int i = t; i < n; i += 256) atomicAdd(&hist[binned[base + i] & 255u], 1);
    __syncthreads();
    int v = hist[t];
    s[t] = v;
    __syncthreads();
    for (int off = 1; off < 256; off <<= 1) {
        int tv = (t >= off) ? s[t - off] : 0;
        __syncthreads();
        s[t] += tv;
        __syncthreads();
    }
    loc[t] = s[t] - v;  // exclusive
    int node = b * 256 + t;
    if (node < Nn) rowptr[node] = base + loc[t];
    if (b == NB - 1 && t == 0) rowptr[Nn] = E;
    __syncthreads();
    for (int i = t; i < n; i += 256) {
        unsigned w = binned[base + i];
        int dl = (int)(w & 255u);
        int p = atomicAdd(&cur[dl], 1);
        colA[base + loc[dl] + p] = (int)(w >> 8);
    }
}

// ---------------- Aggregation: h[i] = x[i] + sum_{j in adj(i)} x[j] ----------------

__global__ __launch_bounds__(256) void agg_kernel(const float* __restrict__ X,
                                                  const int* __restrict__ rowptr,
                                                  const int* __restrict__ colidx,
                                                  float* __restrict__ H, int nnodes) {
    int node = blockIdx.x * 4 + (threadIdx.x >> 6);
    if (node >= nnodes) return;
    int lane = threadIdx.x & 63;
    const float2* x2 = (const float2*)X;
    size_t base = (size_t)node * 64 + lane;
    float2 acc = x2[base];
    float2 a1 = {0.f, 0.f};
    int e = rowptr[node], end = rowptr[node + 1];
    for (; e + 3 < end; e += 4) {
        int s0 = colidx[e], s1 = colidx[e + 1], s2 = colidx[e + 2], s3 = colidx[e + 3];
        float2 v0 = x2[(size_t)s0 * 64 + lane];
        float2 v1 = x2[(size_t)s1 * 64 + lane];
        float2 v2 = x2[(size_t)s2 * 64 + lane];
        float2 v3 = x2[(size_t)s3 * 64 + lane];
        acc.x += v0.x + v2.x; acc.y += v0.y + v2.y;
        a1.x  += v1.x + v3.x; a1.y  += v1.y + v3.y;
    }
    for (; e < end; ++e) {
        int s = colidx[e];
        float2 v = x2[(size_t)s * 64 + lane];
        acc.x += v.x; acc.y += v.y;
    }
    acc.x += a1.x; acc.y += a1.y;
    ((float2*)H)[base] = acc;
}

// ---------------- Fused MLP: out = relu( relu(Hin@Wa+ba) @ Wb + bb ) ----------------

__device__ __forceinline__ void gemm_tile(const float* __restrict__ sIn,
                                          const float4* __restrict__ W4,
                                          int rB, int cB, float acc[8][4]) {
#pragma unroll 4
    for (int k4 = 0; k4 < 32; ++k4) {
        float4 w0 = W4[(k4 * 4 + 0) * 32 + cB];
        float4 w1 = W4[(k4 * 4 + 1) * 32 + cB];
        float4 w2 = W4[(k4 * 4 + 2) * 32 + cB];
        float4 w3 = W4[(k4 * 4 + 3) * 32 + cB];
#pragma unroll
        for (int i = 0; i < 8; ++i) {
            float4 h = *(const float4*)&sIn[(rB + i) * 128 + k4 * 4];
            acc[i][0] = fmaf(h.x, w0.x, fmaf(h.y, w1.x, fmaf(h.z, w2.x, fmaf(h.w, w3.x, acc[i][0]))));
            acc[i][1] = fmaf(h.x, w0.y, fmaf(h.y, w1.y, fmaf(h.z, w2.y, fmaf(h.w, w3.y, acc[i][1]))));
            acc[i][2] = fmaf(h.x, w0.z, fmaf(h.y, w1.z, fmaf(h.z, w2.z, fmaf(h.w, w3.z, acc[i][2]))));
            acc[i][3] = fmaf(h.x, w0.w, fmaf(h.y, w1.w, fmaf(h.z, w2.w, fmaf(h.w, w3.w, acc[i][3]))));
        }
    }
}

__global__ __launch_bounds__(256) void mlp_kernel(const float* __restrict__ Hin,
                                                  const float* __restrict__ Wa,
                                                  const float* __restrict__ ba,
                                                  const float* __restrict__ Wb,
                                                  const float* __restrict__ bb,
                                                  float* __restrict__ Out, int nrows) {
    __shared__ float hT[64 * 128];
    __shared__ float tT[64 * 128];
    const int tid = threadIdx.x;
    const int rows0 = blockIdx.x * 64;
    const int nvalid = min(64, nrows - rows0);

    {
        const float4* src = (const float4*)(Hin + (size_t)rows0 * 128);
        float4* dst4 = (float4*)hT;
#pragma unroll
        for (int it = 0; it < 8; ++it) {
            int idx = it * 256 + tid;
            float4 v = {0.f, 0.f, 0.f, 0.f};
            if ((idx >> 5) < nvalid) v = src[idx];
            dst4[idx] = v;
        }
    }
    __syncthreads();

    const int rB = (tid >> 5) * 8;
    const int cB = (tid & 31);

    float acc[8][4];
    {
        float4 bv = ((const float4*)ba)[cB];
#pragma unroll
        for (int i = 0; i < 8; ++i) { acc[i][0] = bv.x; acc[i][1] = bv.y; acc[i][2] = bv.z; acc[i][3] = bv.w; }
    }
    gemm_tile(hT, (const float4*)Wa, rB, cB, acc);
#pragma unroll
    for (int i = 0; i < 8; ++i) {
        float4 tv;
        tv.x = fmaxf(acc[i][0], 0.f); tv.y = fmaxf(acc[i][1], 0.f);
        tv.z = fmaxf(acc[i][2], 0.f); tv.w = fmaxf(acc[i][3], 0.f);
        *(float4*)&tT[(rB + i) * 128 + cB * 4] = tv;
    }
    __syncthreads();

    {
        float4 bv = ((const float4*)bb)[cB];
#pragma unroll
        for (int i = 0; i < 8; ++i) { acc[i][0] = bv.x; acc[i][1] = bv.y; acc[i][2] = bv.z; acc[i][3] = bv.w; }
    }
    gemm_tile(tT, (const float4*)Wb, rB, cB, acc);
#pragma unroll
    for (int i = 0; i < 8; ++i) {
        if (rB + i < nvalid) {
            float4 ov;
            ov.x = fmaxf(acc[i][0], 0.f); ov.y = fmaxf(acc[i][1], 0.f);
            ov.z = fmaxf(acc[i][2], 0.f); ov.w = fmaxf(acc[i][3], 0.f);
            *(float4*)&Out[((size_t)rows0 + rB + i) * 128 + cB * 4] = ov;
        }
    }
}

// ---------------- launch ----------------

extern "C" void kernel_launch(void* const* d_in, const int* in_sizes, int n_in,
                              void* d_out, int out_size, void* d_ws, size_t ws_size,
                              hipStream_t stream) {
    const float* x  = (const float*)d_in[0];
    const int*   ei = (const int*)d_in[1];   // [2,E]: src then dst
    const float* W1a = (const float*)d_in[3];
    const float* b1a = (const float*)d_in[4];
    const float* W1b = (const float*)d_in[5];
    const float* b1b = (const float*)d_in[6];
    const float* W2a = (const float*)d_in[7];
    const float* b2a = (const float*)d_in[8];
    const float* W2b = (const float*)d_in[9];
    const float* b2b = (const float*)d_in[10];
    float* out = (float*)d_out;

    const int Nn = in_sizes[0] / D;
    const int E  = in_sizes[1] / 2;
    const int* srcIdx = ei;
    const int* dstIdx = ei + E;
    const int NB = (Nn + 255) >> 8;   // 256-node buckets

    // workspace layout
    char* w = (char*)d_ws;
    size_t off = 0;
    int* rowptr = (int*)(w + off);     off += (size_t)(Nn + 1) * 4;
    off = (off + 255) & ~(size_t)255;
    int* bucketCnt = (int*)(w + off);  off += (size_t)NB * 4;
    off = (off + 255) & ~(size_t)255;
    int* bucketBase = (int*)(w + off); off += (size_t)(NB + 1) * 4;
    off = (off + 255) & ~(size_t)255;
    int* gCursor = (int*)(w + off);    off += (size_t)NB * 4;
    off = (off + 255) & ~(size_t)255;
    int* colA = (int*)(w + off);       off += (size_t)E * 4;
    off = (off + 255) & ~(size_t)255;
    float* h1 = (float*)(w + off);     // Nn*128 floats
    unsigned* binned = (unsigned*)h1;  // aliases h1 (only used during CSR build)

    const int gBin = (E + EPB - 1) / EPB;

    k_zero<<<(NB + 255) / 256, 256, 0, stream>>>(bucketCnt, NB);
    k_bhist<<<gBin, 256, 0, stream>>>(dstIdx, E, bucketCnt, NB);
    k_bscan<<<1, 256, 0, stream>>>(bucketCnt, NB, E, bucketBase, gCursor);
    k_bin<<<gBin, 256, 0, stream>>>(srcIdx, dstIdx, E, gCursor, binned);
    k_csr<<<NB, 256, 0, stream>>>(binned, bucketBase, rowptr, colA, Nn, E, NB);

    const int gAgg = (Nn + 3) / 4;
    const int gMlp = (Nn + 63) / 64;

    // Layer 1
    agg_kernel<<<gAgg, 256, 0, stream>>>(x, rowptr, colA, h1, Nn);
    mlp_kernel<<<gMlp, 256, 0, stream>>>(h1, W1a, b1a, W1b, b1b, out, Nn);
    // Layer 2
    agg_kernel<<<gAgg, 256, 0, stream>>>(out, rowptr, colA, h1, Nn);
    mlp_kernel<<<gMlp, 256, 0, stream>>>(h1, W2a, b2a, W2b, b2b, out, Nn);
}